// Round 4
// baseline (43.006 us; speedup 1.0000x reference)
//
#include <hip/hip_runtime.h>
#include <cstdint>

#define NTYPES 39
#define NA 64

typedef float float4v __attribute__((ext_vector_type(4)));

__global__ __launch_bounds__(256) void vcharge_kernel(
    const int*   __restrict__ atoms,
    const float* __restrict__ A,
    const float* __restrict__ Q,
    const float* __restrict__ e,
    const float* __restrict__ s,
    const float* __restrict__ alpha,
    const float* __restrict__ beta_p,
    float*       __restrict__ out)
{
  __shared__ float    tab[NTYPES*NTYPES];  // signed |e_b - e_a|^beta by (a,b)
  __shared__ float    bw2[8];              // bond weight by (af | aromboth<<2)
  __shared__ uint32_t PR[NA*5];            // 2-bit packed rows of A, stride 5
  __shared__ unsigned long long MK[NA];    // full 64-bit Af-nonzero row masks
  __shared__ int      TYR[NA];             // ty[i] * NTYPES
  __shared__ float    EI[4*NA];            // per-wave partial e_i

  const int tid  = threadIdx.x;
  const int wid  = tid >> 6;
  const int lane = tid & 63;
  const int m    = blockIdx.x;

  // ---- constant tables (cold prologue, ~6 powf per thread) ----
  const float beta = beta_p[0];
  for (int k = tid; k < NTYPES*NTYPES; k += 256){
    int a = k / NTYPES;
    int b = k - a*NTYPES;
    float d = e[b] - e[a];
    float t = powf(fabsf(d), beta);
    tab[k] = (d > 0.f) ? t : ((d < 0.f) ? -t : 0.f);
  }
  if (tid < 8){
    float a0 = alpha[0], a1 = alpha[1], a2 = alpha[2], a3 = alpha[3];
    int af = tid & 3;
    float bv = (af == 1) ? a0 : ((af == 2) ? a1 : ((af == 3) ? a2 : 0.f));
    if ((tid & 4) && af != 0) bv += a3;   // marom needs Af>0 and both aromatic
    bw2[tid] = bv;
  }

  // ---- phase 1: load 16KB matrix, quantize to 2-bit packed rows in LDS ----
  // thread t: row r = t>>2, cols [16*(t&3), +16)
  {
    const float4v* A4 = (const float4v*)(A + (size_t)m * (NA*NA));
    float4v v0 = A4[tid*4 + 0];
    float4v v1 = A4[tid*4 + 1];
    float4v v2 = A4[tid*4 + 2];
    float4v v3 = A4[tid*4 + 3];
    uint32_t pk = 0;
    #pragma unroll
    for (int c = 0; c < 4; ++c) pk |= ((uint32_t)(int)v0[c]) << (2*c);
    #pragma unroll
    for (int c = 0; c < 4; ++c) pk |= ((uint32_t)(int)v1[c]) << (2*(4+c));
    #pragma unroll
    for (int c = 0; c < 4; ++c) pk |= ((uint32_t)(int)v2[c]) << (2*(8+c));
    #pragma unroll
    for (int c = 0; c < 4; ++c) pk |= ((uint32_t)(int)v3[c]) << (2*(12+c));
    PR[(tid>>2)*5 + (tid&3)] = pk;
  }

  // per-lane atom constants (overlap with phase 1)
  const int ty = atoms[m*NA + lane];
  const float sinv = 1.0f / s[ty];
  const float alpha4 = alpha[4];
  const uint64_t AROM = (1ull<<6)|(1ull<<10)|(1ull<<19)|(1ull<<20)|(1ull<<21)|(1ull<<22)|(1ull<<32);
  const int aromt = (int)((AROM >> ty) & 1ull);
  const unsigned long long aromBits = __ballot(aromt);  // identical per wave
  const int aromsel = aromt << 2;
  if (wid == 0) TYR[lane] = ty * NTYPES;

  __syncthreads();

  // ---- pass A: af 2-bit pack for i in [16*wid,+16) + ballot row masks ----
  const int sh  = 2 * (lane & 15);
  const uint32_t rpw = PR[lane*5 + wid];          // A[lane][16w..16w+15]
  const uint32_t* colbase = &PR[wid*80 + (lane >> 4)];
  uint32_t afpack = 0;
  unsigned long long mymk = 0;
  #pragma unroll
  for (int k = 0; k < 16; ++k){
    uint32_t w   = colbase[k*5];                  // PR[16w+k][lane>>4]
    uint32_t aij = (w >> sh) & 3u;                // A[i][lane]
    uint32_t aji = (rpw >> (2*k)) & 3u;           // A[lane][i]
    uint32_t af  = aij | aji;                     // == Af[i][lane] (disjoint)
    afpack |= af << (2*k);
    unsigned long long bal = __ballot(af != 0u);  // full row-i nonzero mask
    mymk = (lane == k) ? bal : mymk;
  }
  if (lane < 16) MK[wid*16 + lane] = mymk;        // one b64 store per lane<16
  __syncthreads();

  const unsigned long long mkj = MK[lane];        // own row mask (2-way alias)

  // ---- pass B: 16 pairwise terms per lane ----
  float ei = 0.f;
  const int ibase = wid * 16;
  #pragma unroll
  for (int k = 0; k < 16; ++k){
    const int i = ibase + k;                      // wave-uniform
    int af = (int)((afpack >> (2*k)) & 3u);
    int arom_i = (int)((aromBits >> i) & 1ull);
    float bw = bw2[af + (arom_i ? aromsel : 0)];
    unsigned long long mki = MK[i];               // uniform LDS broadcast
    int one3 = ((mki & mkj) != 0ull);
    float wgt = bw + (one3 ? alpha4 : 0.f);
    ei = fmaf(wgt, tab[TYR[i] + ty], ei);         // TYR[i] uniform broadcast
  }
  EI[wid*NA + lane] = ei;
  __syncthreads();

  // ---- epilogue: wave 0 combines partials, solves, writes ----
  if (wid == 0){
    float eif = EI[lane] + EI[NA + lane] + EI[2*NA + lane] + EI[3*NA + lane];
    float esv = eif * sinv;
    float sv  = sinv;
    #pragma unroll
    for (int off = 32; off; off >>= 1){
      esv += __shfl_xor(esv, off);
      sv  += __shfl_xor(sv,  off);
    }
    const float lam = (Q[m] + esv) / sv;
    out[(size_t)m*NA + lane] = sinv * (lam - eif);
  }
}

extern "C" void kernel_launch(void* const* d_in, const int* in_sizes, int n_in,
                              void* d_out, int out_size, void* d_ws, size_t ws_size,
                              hipStream_t stream)
{
  const int*   atoms = (const int*)  d_in[0];
  const float* A     = (const float*)d_in[1];
  const float* Q     = (const float*)d_in[2];
  const float* e     = (const float*)d_in[3];
  const float* s     = (const float*)d_in[4];
  const float* alpha = (const float*)d_in[5];
  const float* beta  = (const float*)d_in[6];
  float* out = (float*)d_out;

  const int B = in_sizes[2];                 // Q: one entry per molecule
  hipLaunchKernelGGL(vcharge_kernel, dim3(B), dim3(256), 0, stream,
                     atoms, A, Q, e, s, alpha, beta, out);
}

// Round 5
// 27.443 us; speedup vs baseline: 1.5671x; 1.5671x over previous
//
#include <hip/hip_runtime.h>
#include <cstdint>

#define NTYPES 39
#define NA 64
#define TABN (NTYPES*NTYPES)   // 1521

typedef float float4v __attribute__((ext_vector_type(4)));

// ---- kernel A: fill type-pair table + bond-weight table into workspace ----
__global__ __launch_bounds__(256) void table_kernel(
    const float* __restrict__ e,
    const float* __restrict__ alpha,
    const float* __restrict__ beta_p,
    float* __restrict__ ws)
{
  const int k = blockIdx.x * 256 + threadIdx.x;
  if (k < TABN){
    int a = k / NTYPES;
    int b = k - a*NTYPES;
    float d = e[b] - e[a];
    float beta = beta_p[0];
    float t = powf(fabsf(d), beta);
    ws[k] = (d > 0.f) ? t : ((d < 0.f) ? -t : 0.f);
  } else if (k < TABN + 8){
    int q = k - TABN;
    float a0 = alpha[0], a1 = alpha[1], a2 = alpha[2], a3 = alpha[3];
    int af = q & 3;
    float bv = (af == 1) ? a0 : ((af == 2) ? a1 : ((af == 3) ? a2 : 0.f));
    if ((q & 4) && af != 0) bv += a3;   // marom needs Af>0 and both aromatic
    ws[k] = bv;
  }
}

// ---- kernel B: per-molecule charge solve ----
__global__ __launch_bounds__(256) void vcharge_kernel(
    const int*   __restrict__ atoms,
    const float* __restrict__ A,
    const float* __restrict__ Q,
    const float* __restrict__ s,
    const float* __restrict__ alpha,
    const float* __restrict__ ws,
    float*       __restrict__ out)
{
  __shared__ float    tab[TABN];           // signed |e_b - e_a|^beta by (a,b)
  __shared__ float    bw2[8];              // bond weight by (af | aromboth<<2)
  __shared__ uint32_t PR[NA*5];            // 2-bit packed rows of A, stride 5
  __shared__ unsigned long long MK[NA];    // 64-bit Af-nonzero row masks
  __shared__ int      TYR[NA];             // ty[i] * NTYPES
  __shared__ float    EI[4*NA];            // per-wave partial e_i

  const int tid  = threadIdx.x;
  const int wid  = tid >> 6;
  const int lane = tid & 63;
  const int m    = blockIdx.x;

  // ---- copy tables from workspace (coalesced, L2-hot) ----
  for (int k = tid; k < TABN + 8; k += 256){
    float v = ws[k];
    if (k < TABN) tab[k] = v; else bw2[k - TABN] = v;
  }

  // ---- phase 1: load 16KB matrix, quantize to 2-bit packed rows in LDS ----
  // thread t: row r = t>>2, cols [16*(t&3), +16)
  {
    const float4v* A4 = (const float4v*)(A + (size_t)m * (NA*NA));
    float4v v0 = A4[tid*4 + 0];
    float4v v1 = A4[tid*4 + 1];
    float4v v2 = A4[tid*4 + 2];
    float4v v3 = A4[tid*4 + 3];
    uint32_t pk = 0;
    #pragma unroll
    for (int c = 0; c < 4; ++c) pk |= ((uint32_t)(int)v0[c]) << (2*c);
    #pragma unroll
    for (int c = 0; c < 4; ++c) pk |= ((uint32_t)(int)v1[c]) << (2*(4+c));
    #pragma unroll
    for (int c = 0; c < 4; ++c) pk |= ((uint32_t)(int)v2[c]) << (2*(8+c));
    #pragma unroll
    for (int c = 0; c < 4; ++c) pk |= ((uint32_t)(int)v3[c]) << (2*(12+c));
    PR[(tid>>2)*5 + (tid&3)] = pk;
  }

  // per-lane atom constants (overlap with phase 1)
  const int ty = atoms[m*NA + lane];
  const float sinv = 1.0f / s[ty];
  const float alpha4 = alpha[4];
  const uint64_t AROM = (1ull<<6)|(1ull<<10)|(1ull<<19)|(1ull<<20)|(1ull<<21)|(1ull<<22)|(1ull<<32);
  const int aromt = (int)((AROM >> ty) & 1ull);
  const unsigned long long aromBits = __ballot(aromt);  // identical per wave
  const int aromsel = aromt << 2;
  if (wid == 0) TYR[lane] = ty * NTYPES;

  __syncthreads();

  // ---- pass A: af 2-bit pack for i in [16*wid,+16) + ballot row masks ----
  const int sh  = 2 * (lane & 15);
  const uint32_t rpw = PR[lane*5 + wid];          // A[lane][16w..16w+15]
  const uint32_t* colbase = &PR[wid*80 + (lane >> 4)];
  uint32_t afpack = 0;
  unsigned long long mymk = 0;
  #pragma unroll
  for (int k = 0; k < 16; ++k){
    uint32_t w   = colbase[k*5];                  // PR[16w+k][lane>>4]
    uint32_t aij = (w >> sh) & 3u;                // A[i][lane]
    uint32_t aji = (rpw >> (2*k)) & 3u;           // A[lane][i]
    uint32_t af  = aij | aji;                     // == Af[i][lane] (disjoint)
    afpack |= af << (2*k);
    unsigned long long bal = __ballot(af != 0u);  // full row-i nonzero mask
    mymk = (lane == k) ? bal : mymk;
  }
  if (lane < 16) MK[wid*16 + lane] = mymk;        // one b64 store per lane<16
  __syncthreads();

  const unsigned long long mkj = MK[lane];        // own row mask (2-way alias)

  // ---- pass B: 16 pairwise terms per lane ----
  float ei = 0.f;
  const int ibase = wid * 16;
  #pragma unroll
  for (int k = 0; k < 16; ++k){
    const int i = ibase + k;                      // wave-uniform
    int af = (int)((afpack >> (2*k)) & 3u);
    int arom_i = (int)((aromBits >> i) & 1ull);
    float bw = bw2[af + (arom_i ? aromsel : 0)];
    unsigned long long mki = MK[i];               // uniform LDS broadcast
    int one3 = ((mki & mkj) != 0ull);
    float wgt = bw + (one3 ? alpha4 : 0.f);
    ei = fmaf(wgt, tab[TYR[i] + ty], ei);         // TYR[i] uniform broadcast
  }
  EI[wid*NA + lane] = ei;
  __syncthreads();

  // ---- epilogue: wave 0 combines partials, solves, writes ----
  if (wid == 0){
    float eif = EI[lane] + EI[NA + lane] + EI[2*NA + lane] + EI[3*NA + lane];
    float esv = eif * sinv;
    float sv  = sinv;
    #pragma unroll
    for (int off = 32; off; off >>= 1){
      esv += __shfl_xor(esv, off);
      sv  += __shfl_xor(sv,  off);
    }
    const float lam = (Q[m] + esv) / sv;
    out[(size_t)m*NA + lane] = sinv * (lam - eif);
  }
}

extern "C" void kernel_launch(void* const* d_in, const int* in_sizes, int n_in,
                              void* d_out, int out_size, void* d_ws, size_t ws_size,
                              hipStream_t stream)
{
  const int*   atoms = (const int*)  d_in[0];
  const float* A     = (const float*)d_in[1];
  const float* Q     = (const float*)d_in[2];
  const float* e     = (const float*)d_in[3];
  const float* s     = (const float*)d_in[4];
  const float* alpha = (const float*)d_in[5];
  const float* beta  = (const float*)d_in[6];
  float* out = (float*)d_out;
  float* ws  = (float*)d_ws;   // 1529 floats used

  const int B = in_sizes[2];                 // Q: one entry per molecule
  hipLaunchKernelGGL(table_kernel, dim3((TABN + 8 + 255)/256), dim3(256), 0, stream,
                     e, alpha, beta, ws);
  hipLaunchKernelGGL(vcharge_kernel, dim3(B), dim3(256), 0, stream,
                     atoms, A, Q, s, alpha, ws, out);
}

// Round 7
// 25.432 us; speedup vs baseline: 1.6910x; 1.0791x over previous
//
#include <hip/hip_runtime.h>
#include <cstdint>

#define NTYPES 39
#define NA 64
#define TABN (NTYPES*NTYPES)   // 1521
#define TABPAD 1536            // float4-aligned table extent in ws / LDS

typedef float float4v __attribute__((ext_vector_type(4)));

// ---- kernel A: fill type-pair table + bond-weight table into workspace ----
__global__ __launch_bounds__(256) void table_kernel(
    const float* __restrict__ e,
    const float* __restrict__ alpha,
    const float* __restrict__ beta_p,
    float* __restrict__ ws)
{
  const int k = blockIdx.x * 256 + threadIdx.x;
  if (k < TABN){
    int a = k / NTYPES;
    int b = k - a*NTYPES;
    float d = e[b] - e[a];
    float t = powf(fabsf(d), beta_p[0]);
    ws[k] = (d > 0.f) ? t : ((d < 0.f) ? -t : 0.f);
  } else if (k < TABPAD){
    ws[k] = 0.f;                         // pad so float4 copy reads defined data
  } else if (k < TABPAD + 8){
    int q = k - TABPAD;
    float a0 = alpha[0], a1 = alpha[1], a2 = alpha[2], a3 = alpha[3];
    int af = q & 3;
    float bv = (af == 1) ? a0 : ((af == 2) ? a1 : ((af == 3) ? a2 : 0.f));
    if ((q & 4) && af != 0) bv += a3;    // marom needs Af>0 and both aromatic
    ws[k] = bv;
  }
}

// ---- kernel B: per-molecule charge solve ----
__global__ __launch_bounds__(256) void vcharge_kernel(
    const int*   __restrict__ atoms,
    const float* __restrict__ A,
    const float* __restrict__ Q,
    const float* __restrict__ s,
    const float* __restrict__ alpha,
    const float* __restrict__ ws,
    float*       __restrict__ out)
{
  __shared__ float    tab[TABPAD];         // signed |e_b - e_a|^beta by (a,b)
  __shared__ float    bw2[8];              // bond weight by (af | aromboth<<2)
  __shared__ uint32_t PR[NA*5];            // 2-bit packed rows of A, stride 5
  __shared__ unsigned long long MK[NA];    // 64-bit Af-nonzero row masks
  __shared__ int      TYR[NA];             // ty[i] * NTYPES
  __shared__ float    EI[4*NA];            // per-wave partial e_i

  const int tid  = threadIdx.x;
  const int wid  = tid >> 6;
  const int lane = tid & 63;
  const int m    = blockIdx.x;

  // ---- copy tables from workspace (float4, L2-hot) ----
  {
    const float4v* w4 = (const float4v*)ws;
    float4v* t4 = (float4v*)tab;
    t4[tid] = w4[tid];                                  // 256 float4
    if (tid < TABPAD/4 - 256) t4[256 + tid] = w4[256 + tid];  // 128 float4
    if (tid < 8) bw2[tid] = ws[TABPAD + tid];
  }

  // ---- phase 1: load 16KB matrix, quantize to 2-bit packed rows in LDS ----
  // thread t: row r = t>>2, cols [16*(t&3), +16)
  {
    const float4v* A4 = (const float4v*)(A + (size_t)m * (NA*NA));
    float4v v0 = A4[tid*4 + 0];
    float4v v1 = A4[tid*4 + 1];
    float4v v2 = A4[tid*4 + 2];
    float4v v3 = A4[tid*4 + 3];
    uint32_t pk = 0;
    #pragma unroll
    for (int c = 0; c < 4; ++c) pk |= ((uint32_t)(int)v0[c]) << (2*c);
    #pragma unroll
    for (int c = 0; c < 4; ++c) pk |= ((uint32_t)(int)v1[c]) << (2*(4+c));
    #pragma unroll
    for (int c = 0; c < 4; ++c) pk |= ((uint32_t)(int)v2[c]) << (2*(8+c));
    #pragma unroll
    for (int c = 0; c < 4; ++c) pk |= ((uint32_t)(int)v3[c]) << (2*(12+c));
    PR[(tid>>2)*5 + (tid&3)] = pk;
  }

  // per-lane atom constants (overlap with phase 1)
  const int ty = atoms[m*NA + lane];
  const float sinv = 1.0f / s[ty];
  const float alpha4 = alpha[4];
  const uint64_t AROM = (1ull<<6)|(1ull<<10)|(1ull<<19)|(1ull<<20)|(1ull<<21)|(1ull<<22)|(1ull<<32);
  const int aromt = (int)((AROM >> ty) & 1ull);
  const unsigned long long aromBits = __ballot(aromt);  // identical per wave
  const int aromsel = aromt << 2;
  if (wid == 0) TYR[lane] = ty * NTYPES;

  __syncthreads();

  // ---- pass A (fused): af + ballot row masks + bond-term FMA + tab stash ----
  const int sh  = 2 * (lane & 15);
  const uint32_t rpw = PR[lane*5 + wid];          // A[lane][16w..16w+15]
  const uint32_t* colbase = &PR[wid*80 + (lane >> 4)];
  const int ibase = wid * 16;
  float tv[16];                                   // stashed tab values (VGPRs)
  float ei = 0.f;
  unsigned long long mymk = 0;                    // own row mask (lane<16 valid)
  #pragma unroll
  for (int k = 0; k < 16; ++k){
    uint32_t w   = colbase[k*5];                  // PR[16w+k][lane>>4]
    uint32_t aij = (w >> sh) & 3u;                // A[i][lane]
    uint32_t aji = (rpw >> (2*k)) & 3u;           // A[lane][i]
    uint32_t af  = aij | aji;                     // == Af[i][lane] (disjoint)
    unsigned long long bal = __ballot(af != 0u);  // full row-i nonzero mask
    mymk = (lane == k) ? bal : mymk;
    int arom_i = (int)((aromBits >> (ibase + k)) & 1ull);  // uniform
    float bw = bw2[af + (arom_i ? aromsel : 0)];
    float t  = tab[TYR[ibase + k] + ty];          // uniform row + per-lane col
    tv[k] = t;
    ei = fmaf(bw, t, ei);
  }
  if (lane < 16) MK[ibase + lane] = mymk;
  __syncthreads();

  // ---- pass B: one3 term only (alpha4 * tab, gated by mask intersection) ----
  const unsigned long long mkj = MK[lane];        // own row mask
  #pragma unroll
  for (int k = 0; k < 16; ++k){
    unsigned long long mki = MK[ibase + k];       // uniform LDS broadcast
    float add = ((mki & mkj) != 0ull) ? alpha4 : 0.f;
    ei = fmaf(add, tv[k], ei);
  }
  EI[wid*NA + lane] = ei;
  __syncthreads();

  // ---- epilogue: wave 0 combines partials, solves, writes ----
  if (wid == 0){
    float eif = EI[lane] + EI[NA + lane] + EI[2*NA + lane] + EI[3*NA + lane];
    float esv = eif * sinv;
    float sv  = sinv;
    #pragma unroll
    for (int off = 32; off; off >>= 1){
      esv += __shfl_xor(esv, off);
      sv  += __shfl_xor(sv,  off);
    }
    const float lam = (Q[m] + esv) / sv;
    out[(size_t)m*NA + lane] = sinv * (lam - eif);
  }
}

extern "C" void kernel_launch(void* const* d_in, const int* in_sizes, int n_in,
                              void* d_out, int out_size, void* d_ws, size_t ws_size,
                              hipStream_t stream)
{
  const int*   atoms = (const int*)  d_in[0];
  const float* A     = (const float*)d_in[1];
  const float* Q     = (const float*)d_in[2];
  const float* e     = (const float*)d_in[3];
  const float* s     = (const float*)d_in[4];
  const float* alpha = (const float*)d_in[5];
  const float* beta  = (const float*)d_in[6];
  float* out = (float*)d_out;
  float* ws  = (float*)d_ws;   // TABPAD+8 floats used

  const int B = in_sizes[2];                 // Q: one entry per molecule
  hipLaunchKernelGGL(table_kernel, dim3((TABPAD + 8 + 255)/256), dim3(256), 0, stream,
                     e, alpha, beta, ws);
  hipLaunchKernelGGL(vcharge_kernel, dim3(B), dim3(256), 0, stream,
                     atoms, A, Q, s, alpha, ws, out);
}

// Round 8
// 24.574 us; speedup vs baseline: 1.7501x; 1.0349x over previous
//
#include <hip/hip_runtime.h>
#include <cstdint>

#define NTYPES 39
#define NA 64
#define TABN (NTYPES*NTYPES)   // 1521

typedef float float4v __attribute__((ext_vector_type(4)));
typedef int   int4v   __attribute__((ext_vector_type(4)));

__global__ __launch_bounds__(256) void vcharge_kernel(
    const int*   __restrict__ atoms,
    const float* __restrict__ A,
    const float* __restrict__ Q,
    const float* __restrict__ e,
    const float* __restrict__ s,
    const float* __restrict__ alpha,
    const float* __restrict__ beta_p,
    float*       __restrict__ out)
{
  __shared__ float    tab[TABN];           // signed |e_b - e_a|^beta by (a,b)
  __shared__ float    bw2[8];              // bond weight by (af | aromboth<<2)
  __shared__ uint32_t PRT[4*68];           // 2-bit cols, transposed [word][row], pad 68
  __shared__ unsigned long long MK[NA];    // 64-bit Af-nonzero row masks
  __shared__ float    EI[4*NA];            // per-wave partial e_i

  const int tid  = threadIdx.x;
  const int wid  = tid >> 6;
  const int lane = tid & 63;
  const int m    = blockIdx.x;

  // ---- in-kernel table fill: native v_exp/v_log (≈5 ops/entry, 6/thread) ----
  const float beta = beta_p[0];
  for (int k = tid; k < TABN; k += 256){
    int a = k / NTYPES;
    int b = k - a*NTYPES;
    float d = e[b] - e[a];
    float t = exp2f(beta * log2f(fabsf(d)));   // d==0: log2->-inf, exp2->0
    tab[k] = (d > 0.f) ? t : ((d < 0.f) ? -t : 0.f);
  }
  if (tid < 8){
    float a0 = alpha[0], a1 = alpha[1], a2 = alpha[2], a3 = alpha[3];
    int af = tid & 3;
    float bv = (af == 1) ? a0 : ((af == 2) ? a1 : ((af == 3) ? a2 : 0.f));
    if ((tid & 4) && af != 0) bv += a3;   // marom needs Af>0 and both aromatic
    bw2[tid] = bv;
  }

  // ---- phase 1: load 16KB matrix, quantize via float Horner, store transposed ----
  // thread t: row r = t>>2, cols [16*(t&3), +16)
  {
    const float4v* A4 = (const float4v*)(A + (size_t)m * (NA*NA));
    float4v v0 = A4[tid*4 + 0];
    float4v v1 = A4[tid*4 + 1];
    float4v v2 = A4[tid*4 + 2];
    float4v v3 = A4[tid*4 + 3];
    // digits are exact small ints; Horner in float is exact (<=65535)
    float flo = v1[3];
    flo = fmaf(flo, 4.f, v1[2]); flo = fmaf(flo, 4.f, v1[1]);
    flo = fmaf(flo, 4.f, v1[0]); flo = fmaf(flo, 4.f, v0[3]);
    flo = fmaf(flo, 4.f, v0[2]); flo = fmaf(flo, 4.f, v0[1]);
    flo = fmaf(flo, 4.f, v0[0]);
    float fhi = v3[3];
    fhi = fmaf(fhi, 4.f, v3[2]); fhi = fmaf(fhi, 4.f, v3[1]);
    fhi = fmaf(fhi, 4.f, v3[0]); fhi = fmaf(fhi, 4.f, v2[3]);
    fhi = fmaf(fhi, 4.f, v2[2]); fhi = fmaf(fhi, 4.f, v2[1]);
    fhi = fmaf(fhi, 4.f, v2[0]);
    uint32_t pk = (uint32_t)flo | ((uint32_t)fhi << 16);
    PRT[(tid & 3)*68 + (tid >> 2)] = pk;   // transposed: [word][row]
  }

  // per-lane atom constants (overlap with phase 1)
  const int ty = atoms[m*NA + lane];
  const float sinv = 1.0f / s[ty];
  const float alpha4 = alpha[4];
  const uint64_t AROM = (1ull<<6)|(1ull<<10)|(1ull<<19)|(1ull<<20)|(1ull<<21)|(1ull<<22)|(1ull<<32);
  const int aromt = (int)((AROM >> ty) & 1ull);
  const unsigned long long aromBits = __ballot(aromt);  // identical per wave
  const int aromsel = aromt << 2;

  __syncthreads();

  // ---- pass A (fused): af + ballot row masks + bond-term FMA + tab stash ----
  const int sh  = 2 * (lane & 15);
  const uint32_t rpw = PRT[wid*68 + lane];        // A[lane][16w..16w+16)
  const int4v* cb = (const int4v*)&PRT[(lane >> 4)*68 + wid*16];
  const int ibase = wid * 16;
  float tv[16];                                   // stashed tab values (VGPRs)
  float ei = 0.f;
  unsigned long long mymk = 0;                    // own row mask (lane<16 valid)
  #pragma unroll
  for (int c = 0; c < 4; ++c){
    int4v cw = cb[c];                             // 4 col-words, conflict-free b128
    #pragma unroll
    for (int q = 0; q < 4; ++q){
      const int k = c*4 + q;
      uint32_t w   = (uint32_t)cw[q];             // PRT[lane>>4][16w+k]
      uint32_t aij = (w >> sh) & 3u;              // A[i][lane]
      uint32_t aji = (rpw >> (2*k)) & 3u;         // A[lane][i]
      uint32_t af  = aij | aji;                   // == Af[i][lane] (disjoint)
      unsigned long long bal = __ballot(af != 0u);// full row-i nonzero mask
      mymk = (lane == k) ? bal : mymk;
      int arom_i = (int)((aromBits >> (ibase + k)) & 1ull);   // uniform scalar
      int idx = (int)af + (aromsel & (0 - arom_i));
      float bw = bw2[idx];
      int tyi = __builtin_amdgcn_readlane(ty, ibase + k);     // uniform lane idx
      float t  = tab[tyi*NTYPES + ty];            // sgpr row + per-lane col
      tv[k] = t;
      ei = fmaf(bw, t, ei);
    }
  }
  if (lane < 16) MK[ibase + lane] = mymk;
  __syncthreads();

  // ---- pass B: one3 term only (alpha4 * tab, gated by mask intersection) ----
  const unsigned long long mkj = MK[lane];        // own row mask
  #pragma unroll
  for (int k = 0; k < 16; ++k){
    unsigned long long mki = MK[ibase + k];       // uniform LDS broadcast
    float add = ((mki & mkj) != 0ull) ? alpha4 : 0.f;
    ei = fmaf(add, tv[k], ei);
  }
  EI[wid*NA + lane] = ei;
  __syncthreads();

  // ---- epilogue: wave 0 combines partials, solves, writes ----
  if (wid == 0){
    float eif = EI[lane] + EI[NA + lane] + EI[2*NA + lane] + EI[3*NA + lane];
    float esv = eif * sinv;
    float sv  = sinv;
    #pragma unroll
    for (int off = 32; off; off >>= 1){
      esv += __shfl_xor(esv, off);
      sv  += __shfl_xor(sv,  off);
    }
    const float lam = (Q[m] + esv) / sv;
    out[(size_t)m*NA + lane] = sinv * (lam - eif);
  }
}

extern "C" void kernel_launch(void* const* d_in, const int* in_sizes, int n_in,
                              void* d_out, int out_size, void* d_ws, size_t ws_size,
                              hipStream_t stream)
{
  const int*   atoms = (const int*)  d_in[0];
  const float* A     = (const float*)d_in[1];
  const float* Q     = (const float*)d_in[2];
  const float* e     = (const float*)d_in[3];
  const float* s     = (const float*)d_in[4];
  const float* alpha = (const float*)d_in[5];
  const float* beta  = (const float*)d_in[6];
  float* out = (float*)d_out;

  const int B = in_sizes[2];                 // Q: one entry per molecule
  hipLaunchKernelGGL(vcharge_kernel, dim3(B), dim3(256), 0, stream,
                     atoms, A, Q, e, s, alpha, beta, out);
}